// Round 13
// baseline (265.648 us; speedup 1.0000x reference)
//
#include <hip/hip_runtime.h>
#include <math.h>

namespace {
constexpr int BB = 8;
constexpr int CH = 256;
constexpr int CQ = 32;
constexpr int NN = 4096;
}

typedef float f32x4 __attribute__((ext_vector_type(4)));
typedef short bf16x8 __attribute__((ext_vector_type(8)));
typedef unsigned short us8 __attribute__((ext_vector_type(8)));

#define MFMA16(a, b, c) __builtin_amdgcn_mfma_f32_16x16x32_bf16(a, b, c, 0, 0, 0)
#define LOG2E 1.4426950408889634f

__device__ __forceinline__ unsigned short f2bf(float x) {
    unsigned int u = __float_as_uint(x);
    u += 0x7fffu + ((u >> 16) & 1u);
    return (unsigned short)(u >> 16);
}
__device__ __forceinline__ float bf2f(unsigned short h) {
    return __uint_as_float(((unsigned int)h) << 16);
}
__device__ __forceinline__ void gload16(const void* g, void* l) {
    __builtin_amdgcn_global_load_lds(
        (const __attribute__((address_space(1))) unsigned int*)g,
        (__attribute__((address_space(3))) unsigned int*)l, 16, 0, 0);
}

// ---------------------------------------------------------------------------
// Kernel 0: split W (wq|wk|wv concat, 320x256) into bf16 hi/lo.
// ---------------------------------------------------------------------------
__global__ __launch_bounds__(256) void wsplit_kernel(
    const float* __restrict__ wq, const float* __restrict__ wk,
    const float* __restrict__ wv,
    unsigned short* __restrict__ wh, unsigned short* __restrict__ wl)
{
    int idx = blockIdx.x * 256 + threadIdx.x;   // 0..81919
    float v;
    if (idx < 8192)       v = wq[idx];
    else if (idx < 16384) v = wk[idx - 8192];
    else                  v = wv[idx - 16384];
    unsigned short hi = f2bf(v);
    wh[idx] = hi;
    wl[idx] = f2bf(v - bf2f(hi));
}

// ---------------------------------------------------------------------------
// Kernel 1 (fused transpose+proj, 32-PIXEL TILES for 4 blocks/CU): proj has
// NO cross-block locality constraint (x tiles disjoint, W 320KB shared), so
// unlike attn its occupancy can be doubled safely. Grid 1024 = b x 128
// tiles; LDS 32KB (xh 16K + xl 16K); __launch_bounds__(256,4).
// Pipeline: 4 super-steps, each {issue loads pass s+1 -> GEMM(2s),GEMM(2s+1)
// (120 MFMAs hide load latency) -> convert+write pass s+1 -> barrier}.
// Read chunks {8s..8s+7} and write chunks {8s+8..8s+15} are disjoint under
// the shared XOR swizzle -> race-free. GEMM math identical (acc[5][2]).
// ---------------------------------------------------------------------------
__global__ __launch_bounds__(256, 4) void proj_kernel(
    const float* __restrict__ x,
    const unsigned short* __restrict__ wh, const unsigned short* __restrict__ wl,
    const float* __restrict__ bq, const float* __restrict__ bk,
    const float* __restrict__ bv,
    unsigned short* __restrict__ qh, unsigned short* __restrict__ ql,
    unsigned short* __restrict__ kh, unsigned short* __restrict__ kl,
    unsigned short* __restrict__ vt)
{
    __shared__ __align__(16) unsigned char smem[32768];
    const int t    = threadIdx.x;
    const int lane = t & 63;
    const int w    = t >> 6;
    const int l16  = lane & 15;
    const int quad = lane >> 4;
    const int b    = blockIdx.x >> 7;
    const int n0   = (blockIdx.x & 127) << 5;   // 32-pixel tiles

    const float* xB = x + (size_t)b * 256 * NN + n0;
    const int n   = t & 31;        // pixel row 0..31
    const int cg0 = t >> 5;        // chunk-group 0..7

    // ---- prologue: stage pass 0 (chunks 0..7; loads exposed once) ----
    {
        int cc = cg0;
        float v[8];
        #pragma unroll
        for (int j = 0; j < 8; ++j)
            v[j] = xB[(size_t)(cc * 8 + j) * NN + n];
        us8 h8, l8;
        #pragma unroll
        for (int j = 0; j < 8; ++j) {
            unsigned short hi = f2bf(v[j]);
            h8[j] = hi;
            l8[j] = f2bf(v[j] - bf2f(hi));
        }
        int off = n * 512 + ((cc ^ (n & 7)) << 4);
        *(us8*)(smem + off) = h8;
        *(us8*)(smem + 16384 + off) = l8;
    }
    __syncthreads();

    f32x4 acc[5][2] = {};
    #pragma unroll 1
    for (int s = 0; s < 4; ++s) {
        // ---- issue loads for pass s+1 (consumed after the GEMMs below) ----
        float vnext[8];
        if (s < 3) {
            int cc = (s + 1) * 8 + cg0;
            #pragma unroll
            for (int j = 0; j < 8; ++j)
                vnext[j] = xB[(size_t)(cc * 8 + j) * NN + n];
        }

        // ---- GEMM(2s), GEMM(2s+1): 120 MFMAs hide the vnext latency ----
        #pragma unroll
        for (int kh2 = 0; kh2 < 2; ++kh2) {
            int kc = s * 2 + kh2;
            bf16x8 ah[5], al[5];
            #pragma unroll
            for (int i = 0; i < 5; ++i) {
                int och = (w * 5 + i) * 16 + l16;
                ah[i] = *(const bf16x8*)(wh + och * 256 + kc * 32 + quad * 8);
                al[i] = *(const bf16x8*)(wl + och * 256 + kc * 32 + quad * 8);
            }
            #pragma unroll
            for (int nt = 0; nt < 2; ++nt) {
                int roff = (nt * 16 + l16) * 512
                         + (((kc * 4 + quad) ^ (l16 & 7)) * 16);
                bf16x8 bh = *(const bf16x8*)(smem + roff);
                bf16x8 bl = *(const bf16x8*)(smem + 16384 + roff);
                #pragma unroll
                for (int i = 0; i < 5; ++i) {
                    acc[i][nt] = MFMA16(ah[i], bh, acc[i][nt]);
                    acc[i][nt] = MFMA16(al[i], bh, acc[i][nt]);
                    acc[i][nt] = MFMA16(ah[i], bl, acc[i][nt]);
                }
            }
        }

        // ---- convert + write pass s+1 (disjoint chunk slots vs reads) ----
        if (s < 3) {
            int cc = (s + 1) * 8 + cg0;
            us8 h8, l8;
            #pragma unroll
            for (int j = 0; j < 8; ++j) {
                unsigned short hi = f2bf(vnext[j]);
                h8[j] = hi;
                l8[j] = f2bf(vnext[j] - bf2f(hi));
            }
            int off = n * 512 + ((cc ^ (n & 7)) << 4);
            *(us8*)(smem + off) = h8;
            *(us8*)(smem + 16384 + off) = l8;
        }
        __syncthreads();   // pass s+1 visible; GEMM reads of s drained
    }

    // ---- epilogue: bias add, split/pack into LDS (aliases x-tile) ----
    // layout: q/k arrays 4 x 2KB at 0; v stage 256 x 72B at 8192 (26.6KB tot)
    #pragma unroll
    for (int i = 0; i < 5; ++i) {
        int tile = w * 5 + i;
        if (tile < 4) {
            #pragma unroll
            for (int r = 0; r < 4; ++r) {
                int och = tile * 16 + quad * 4 + r;
                float bias = (och < 32) ? bq[och] : bk[och - 32];
                int arr = (och < 32) ? 0 : 2;
                int oq = och & 31;
                #pragma unroll
                for (int nt = 0; nt < 2; ++nt) {
                    float val = acc[i][nt][r] + bias;
                    if (och < 32) val *= LOG2E;
                    unsigned short hi = f2bf(val);
                    unsigned short lo = f2bf(val - bf2f(hi));
                    *(unsigned short*)(smem + arr * 2048 + (nt * 16 + l16) * 64 + oq * 2) = hi;
                    *(unsigned short*)(smem + (arr + 1) * 2048 + (nt * 16 + l16) * 64 + oq * 2) = lo;
                }
            }
        } else {
            #pragma unroll
            for (int r = 0; r < 4; ++r) {
                int voch = tile * 16 + quad * 4 + r - 64;
                float bias = bv[voch];
                #pragma unroll
                for (int nt = 0; nt < 2; ++nt) {
                    *(unsigned short*)(smem + 8192 + voch * 72 + (nt * 16 + l16) * 2)
                        = f2bf(acc[i][nt][r] + bias);
                }
            }
        }
    }
    __syncthreads();

    // copy-out q/k: 4 arrays x 32 rows x 64B (contiguous 2KB per array)
    {
        unsigned short* dsts[4] = { qh, ql, kh, kl };
        int arr = t >> 6, sub = t & 63;
        int row = sub >> 1, half = sub & 1;
        unsigned short* dst = dsts[arr] + ((size_t)b * NN + n0 + row) * 32 + half * 16;
        *(us8*)(dst)     = *(const us8*)(smem + arr * 2048 + row * 64 + half * 32);
        *(us8*)(dst + 8) = *(const us8*)(smem + arr * 2048 + row * 64 + half * 32 + 8 * 2);
    }
    // copy-out v: 256 voch rows x 64B (one row per thread)
    {
        int voch = t;
        unsigned short* dst = vt + ((size_t)b * CH + voch) * NN + n0;
        #pragma unroll
        for (int i = 0; i < 4; ++i)
            *(us8*)(dst + i * 8) = *(const us8*)(smem + 8192 + voch * 72 + i * 16);
    }
}

// ---------------------------------------------------------------------------
// Kernel 3: MFMA flash attention -- ROUND-10/11/12 VERBATIM (proven
// 122.5-124us, FETCH 12.3MB): 512 blocks x 256 thr, b=blockIdx&7, 80KB LDS,
// V dbuf 2x32KB, P dbuf 2x8KB, ONE barrier/tile; E 12-MFMA setprio cluster
// then VALU cluster; PV 16 hoisted LDS reads then one 32-MFMA cluster.
// ---------------------------------------------------------------------------
#define A_P0 0          // P buffer 0: 64 rows x 128B
#define A_P1 8192       // P buffer 1
#define A_V0 16384      // V buffer 0: 256ch x 128B
#define A_V1 49152      // V buffer 1
#define A_SM 16384      // 256 floats, aliases V0 (post-loop only)

__global__ __launch_bounds__(256, 2) void attn_kernel(
    const unsigned short* __restrict__ qh, const unsigned short* __restrict__ ql,
    const unsigned short* __restrict__ kh, const unsigned short* __restrict__ kl,
    const unsigned short* __restrict__ vt, const float* __restrict__ gptr,
    float* __restrict__ out)
{
    __shared__ __align__(16) unsigned char smem[81920];
    const int t    = threadIdx.x;
    const int lane = t & 63;
    const int w    = t >> 6;
    const int l16  = lane & 15;
    const int quad = lane >> 4;
    const int b    = blockIdx.x & 7;
    const int n0   = (blockIdx.x >> 3) << 6;

    // Q B-frags (hi/lo); Q pre-scaled by log2e
    bf16x8 qhA[4], qlA[4];
    #pragma unroll
    for (int qt = 0; qt < 4; ++qt) {
        size_t row = (size_t)b * NN + n0 + qt * 16 + l16;
        qhA[qt] = *(const bf16x8*)(qh + row * 32 + quad * 8);
        qlA[qt] = *(const bf16x8*)(ql + row * 32 + quad * 8);
    }

    // K A-frag base: wave w owns keys w*16..+15 of each 64-key tile
    const unsigned short* khbase = kh + ((size_t)b * NN + w * 16 + l16) * 32 + quad * 8;
    const unsigned short* klbase = kl + ((size_t)b * NN + w * 16 + l16) * 32 + quad * 8;
    const unsigned char*  vtB    = (const unsigned char*)(vt + (size_t)b * CH * NN);

    // hoisted per-thread stage addresses
    const unsigned char* vsrc[8];
    int vlds[8];
    #pragma unroll
    for (int j = 0; j < 8; ++j) {
        int idx = j * 256 + t;
        int r = idx >> 3, cl = idx & 7;
        int cg = cl ^ (r & 7);
        vsrc[j] = vtB + (size_t)r * 8192 + cg * 16;   // tile-0 base
        vlds[j] = idx * 16;
    }
    // P-write offset (lane-constant): row = query l16, key chunk XOR row&7
    const int poff = l16 * 128 + ((((w << 1) | (quad >> 1)) ^ (l16 & 7)) << 4)
                   + ((quad & 1) << 3);

    f32x4 acc[4][4] = {};
    float S[4] = {};

    // prologue: K(0) regs first, then stage V(0) into V0
    bf16x8 kch = *(const bf16x8*)(khbase);
    bf16x8 kcl = *(const bf16x8*)(klbase);
    #pragma unroll
    for (int j = 0; j < 8; ++j)
        gload16(vsrc[j], smem + A_V0 + vlds[j]);

    #pragma unroll 1
    for (int tile = 0; tile < 64; ++tile) {
        unsigned char* P = smem + ((tile & 1) ? A_P1 : A_P0);

        // ---- E, MFMA cluster: all 12 MFMAs back-to-back ----
        f32x4 e4[4];
        __builtin_amdgcn_s_setprio(1);
        #pragma unroll
        for (int qt = 0; qt < 4; ++qt) {
            f32x4 e = { 0.f, 0.f, 0.f, 0.f };
            e = MFMA16(kch, qhA[qt], e);
            e = MFMA16(kch, qlA[qt], e);
            e = MFMA16(kcl, qhA[qt], e);
            e4[qt] = e;
        }
        __builtin_amdgcn_s_setprio(0);

        // ---- E, VALU cluster: exp2 / pack / S / P-write ----
        #pragma unroll
        for (int qt = 0; qt < 4; ++qt) {
            float p0 = exp2f(e4[qt][0]), p1 = exp2f(e4[qt][1]);
            float p2 = exp2f(e4[qt][2]), p3 = exp2f(e4[qt][3]);
            unsigned int u01, u23;
            asm("v_cvt_pk_bf16_f32 %0, %1, %2" : "=v"(u01) : "v"(p0), "v"(p1));
            asm("v_cvt_pk_bf16_f32 %0, %1, %2" : "=v"(u23) : "v"(p2), "v"(p3));
            // S sums the rounded values actually stored in P
            S[qt] += (__uint_as_float(u01 << 16) + __uint_as_float(u01 & 0xffff0000u))
                   + (__uint_as_float(u23 << 16) + __uint_as_float(u23 & 0xffff0000u));
            int2 pk2 = { (int)u01, (int)u23 };
            *(int2*)(P + qt * 2048 + poff) = pk2;
        }

        __syncthreads();   // P(tile) + V(tile) ready; prev PV reads drained

        // ---- post-barrier VMEM issue (consumed after NEXT barrier) ----
        const int m1 = ((tile + 1) & 63) * 64;
        bf16x8 knh = *(const bf16x8*)(khbase + (size_t)m1 * 32);
        bf16x8 knl = *(const bf16x8*)(klbase + (size_t)m1 * 32);
        if (tile < 63) {
            unsigned char* vdst = smem + ((tile & 1) ? A_V0 : A_V1);
            #pragma unroll
            for (int j = 0; j < 8; ++j) {
                vsrc[j] += 128;
                gload16(vsrc[j], vdst + vlds[j]);
            }
        }

        // ---- PV: hoist ALL 16 LDS reads, then one 32-MFMA cluster ----
        const unsigned char* VB = smem + ((tile & 1) ? A_V1 : A_V0);
        bf16x8 af0[4], af1[4], bf0[4], bf1[4];
        #pragma unroll
        for (int qt = 0; qt < 4; ++qt) {
            int row = qt * 16 + l16;
            af0[qt] = *(const bf16x8*)(P + row * 128
                                         + (((0 * 4 + quad) ^ (l16 & 7)) << 4));
            af1[qt] = *(const bf16x8*)(P + row * 128
                                         + (((1 * 4 + quad) ^ (l16 & 7)) << 4));
        }
        #pragma unroll
        for (int ct = 0; ct < 4; ++ct) {
            int vrow = w * 64 + ct * 16 + l16;
            bf0[ct] = *(const bf16x8*)(VB + vrow * 128
                                          + (((0 * 4 + quad) ^ (l16 & 7)) << 4));
            bf1[ct] = *(const bf16x8*)(VB + vrow * 128
                                          + (((1 * 4 + quad) ^ (l16 & 7)) << 4));
        }
        __builtin_amdgcn_s_setprio(1);
        #pragma unroll
        for (int qt = 0; qt < 4; ++qt)
            #pragma unroll
            for (int ct = 0; ct < 4; ++ct)
                acc[qt][ct] = MFMA16(af0[qt], bf0[ct], acc[qt][ct]);
        #pragma unroll
        for (int qt = 0; qt < 4; ++qt)
            #pragma unroll
            for (int ct = 0; ct < 4; ++ct)
                acc[qt][ct] = MFMA16(af1[qt], bf1[ct], acc[qt][ct]);
        __builtin_amdgcn_s_setprio(0);

        kch = knh;
        kcl = knl;
    }

    // S: reduce over quads (same query in lanes l16+16q), then across waves
    #pragma unroll
    for (int mask = 16; mask <= 32; mask <<= 1)
        #pragma unroll
        for (int qt = 0; qt < 4; ++qt)
            S[qt] += __shfl_xor(S[qt], mask);
    float* SM = (float*)(smem + A_SM);
    if (quad == 0) {
        #pragma unroll
        for (int qt = 0; qt < 4; ++qt)
            SM[w * 64 + qt * 16 + l16] = S[qt];
    }
    __syncthreads();

    const float g1 = 1.f + gptr[0];
    float* ob = out + (size_t)b * CH * NN;
    #pragma unroll
    for (int qt = 0; qt < 4; ++qt) {
        float is[4];
        #pragma unroll
        for (int r = 0; r < 4; ++r) {
            int qi = qt * 16 + quad * 4 + r;
            float Sf = SM[qi] + SM[64 + qi] + SM[128 + qi] + SM[192 + qi];
            is[r] = g1 / Sf;
        }
        #pragma unroll
        for (int ct = 0; ct < 4; ++ct) {
            float4 o4;
            o4.x = floorf(acc[qt][ct][0] * is[0] * 256.f) * 0.00390625f;
            o4.y = floorf(acc[qt][ct][1] * is[1] * 256.f) * 0.00390625f;
            o4.z = floorf(acc[qt][ct][2] * is[2] * 256.f) * 0.00390625f;
            o4.w = floorf(acc[qt][ct][3] * is[3] * 256.f) * 0.00390625f;
            *(float4*)(ob + (size_t)(w * 64 + ct * 16 + l16) * NN
                          + n0 + qt * 16 + quad * 4) = o4;
        }
    }
}

// ---------------------------------------------------------------------------
extern "C" void kernel_launch(void* const* d_in, const int* in_sizes, int n_in,
                              void* d_out, int out_size, void* d_ws, size_t ws_size,
                              hipStream_t stream) {
    const float* x  = (const float*)d_in[0];
    const float* wq = (const float*)d_in[1];
    const float* bq = (const float*)d_in[2];
    const float* wk = (const float*)d_in[3];
    const float* bk = (const float*)d_in[4];
    const float* wv = (const float*)d_in[5];
    const float* bv = (const float*)d_in[6];
    const float* gm = (const float*)d_in[7];
    float* out = (float*)d_out;

    unsigned short* ws = (unsigned short*)d_ws;
    const size_t WSZ = 320 * 256;               // 81,920
    const size_t QSZ = (size_t)BB * NN * 32;    // 1,048,576
    const size_t XSZ = (size_t)BB * NN * 256;   // 8,388,608
    unsigned short* wh = ws;
    unsigned short* wl = wh + WSZ;
    unsigned short* qh = wl + WSZ;
    unsigned short* ql = qh + QSZ;
    unsigned short* kh = ql + QSZ;
    unsigned short* kl = kh + QSZ;
    unsigned short* vt = kl + QSZ;              // vt size XSZ

    wsplit_kernel<<<320, 256, 0, stream>>>(wq, wk, wv, wh, wl);
    proj_kernel<<<1024, 256, 0, stream>>>(x, wh, wl, bq, bk, bv,
                                          qh, ql, kh, kl, vt);
    attn_kernel<<<512, 256, 0, stream>>>(qh, ql, kh, kl, vt, gm, out);
}

// Round 14
// 236.021 us; speedup vs baseline: 1.1255x; 1.1255x over previous
//
#include <hip/hip_runtime.h>
#include <math.h>

namespace {
constexpr int BB = 8;
constexpr int CH = 256;
constexpr int CQ = 32;
constexpr int NN = 4096;
}

typedef float f32x4 __attribute__((ext_vector_type(4)));
typedef short bf16x8 __attribute__((ext_vector_type(8)));
typedef unsigned short us8 __attribute__((ext_vector_type(8)));

#define MFMA16(a, b, c) __builtin_amdgcn_mfma_f32_16x16x32_bf16(a, b, c, 0, 0, 0)
#define LOG2E 1.4426950408889634f

__device__ __forceinline__ unsigned short f2bf(float x) {
    unsigned int u = __float_as_uint(x);
    u += 0x7fffu + ((u >> 16) & 1u);
    return (unsigned short)(u >> 16);
}
__device__ __forceinline__ float bf2f(unsigned short h) {
    return __uint_as_float(((unsigned int)h) << 16);
}
__device__ __forceinline__ void gload16(const void* g, void* l) {
    __builtin_amdgcn_global_load_lds(
        (const __attribute__((address_space(1))) unsigned int*)g,
        (__attribute__((address_space(3))) unsigned int*)l, 16, 0, 0);
}

// ---------------------------------------------------------------------------
// Kernel 0: split W (wq|wk|wv concat, 320x256) into bf16 hi/lo.
// ---------------------------------------------------------------------------
__global__ __launch_bounds__(256) void wsplit_kernel(
    const float* __restrict__ wq, const float* __restrict__ wk,
    const float* __restrict__ wv,
    unsigned short* __restrict__ wh, unsigned short* __restrict__ wl)
{
    int idx = blockIdx.x * 256 + threadIdx.x;   // 0..81919
    float v;
    if (idx < 8192)       v = wq[idx];
    else if (idx < 16384) v = wk[idx - 8192];
    else                  v = wv[idx - 16384];
    unsigned short hi = f2bf(v);
    wh[idx] = hi;
    wl[idx] = f2bf(v - bf2f(hi));
}

// ---------------------------------------------------------------------------
// Kernel 1 (fused transpose+proj, OCH-SPLIT for 4 blocks/CU): grid 1024 =
// 512 spatial x 2 och-halves. 64-PIXEL tiles kept (full 128B vt writes --
// round-13's 32-pixel tiles caused 3x write amplification). Half 0: tiles
// 0..11 (q,k,v[0:128]), 3 tiles/wave; half 1: tiles 12..19 (v[128:256]),
// 2 tiles/wave. Each block stages the full 256ch x 64px x-tile via a
// kc-granular DOUBLE BUFFER (2 x 8KB: 64 rows x 64B hi + 64B lo per kc),
// pipelined {issue loads kc+1 -> GEMM(kc) -> convert+write kc+1 -> bar}.
// LDS 33KB max (epilogue h0: q/k 16KB + v128 17.4KB) -> 4 blocks/CU.
// 64B-pitch swizzle: write chunk w^(n&3)^((n>>2)&3), read chunk
// quad^(l16&3)^((l16>>2)&3) (consistent; both at the 8-way b128 floor).
// ---------------------------------------------------------------------------
__global__ __launch_bounds__(256, 4) void proj_kernel(
    const float* __restrict__ x,
    const unsigned short* __restrict__ wh, const unsigned short* __restrict__ wl,
    const float* __restrict__ bq, const float* __restrict__ bk,
    const float* __restrict__ bv,
    unsigned short* __restrict__ qh, unsigned short* __restrict__ ql,
    unsigned short* __restrict__ kh, unsigned short* __restrict__ kl,
    unsigned short* __restrict__ vt)
{
    __shared__ __align__(16) unsigned char smem[33792];
    const int t    = threadIdx.x;
    const int lane = t & 63;
    const int w    = t >> 6;
    const int l16  = lane & 15;
    const int quad = lane >> 4;
    const int b    = blockIdx.x >> 7;
    const int h    = blockIdx.x & 1;                 // och half
    const int n0   = ((blockIdx.x >> 1) & 63) << 6;  // 64-pixel tile
    const int NT   = h ? 2 : 3;                      // tiles per wave

    const float* xB = x + (size_t)b * 256 * NN + n0;
    const int n = lane;                // pixel row this thread stages
    const int woff = n * 64 + ((w ^ (n & 3) ^ ((n >> 2) & 3)) << 4);
    const int rsw  = ((l16 & 3) ^ ((l16 >> 2) & 3));

    // ---- prologue: stage kc=0 into buf0 ----
    {
        float v[8];
        #pragma unroll
        for (int j = 0; j < 8; ++j)
            v[j] = xB[(size_t)(w * 8 + j) * NN + n];
        us8 h8, l8;
        #pragma unroll
        for (int j = 0; j < 8; ++j) {
            unsigned short hi = f2bf(v[j]);
            h8[j] = hi;
            l8[j] = f2bf(v[j] - bf2f(hi));
        }
        *(us8*)(smem + woff) = h8;
        *(us8*)(smem + 4096 + woff) = l8;
    }
    __syncthreads();

    f32x4 acc[3][4] = {};
    #pragma unroll 1
    for (int kc = 0; kc < 8; ++kc) {
        // ---- issue loads for kc+1 (consumed after GEMM below) ----
        float vnext[8];
        if (kc < 7) {
            #pragma unroll
            for (int j = 0; j < 8; ++j)
                vnext[j] = xB[(size_t)((kc + 1) * 32 + w * 8 + j) * NN + n];
        }

        // ---- GEMM(kc) from buf[kc&1] ----
        const int base = (kc & 1) * 8192;
        bf16x8 ah[3], al[3];
        #pragma unroll
        for (int i = 0; i < 3; ++i) {
            if (i < NT) {
                int tile = h ? (12 + w * 2 + i) : (w * 3 + i);
                int och  = tile * 16 + l16;
                ah[i] = *(const bf16x8*)(wh + och * 256 + kc * 32 + quad * 8);
                al[i] = *(const bf16x8*)(wl + och * 256 + kc * 32 + quad * 8);
            }
        }
        #pragma unroll
        for (int nt = 0; nt < 4; ++nt) {
            int roff = (nt * 16 + l16) * 64 + ((quad ^ rsw) << 4);
            bf16x8 bh = *(const bf16x8*)(smem + base + roff);
            bf16x8 bl = *(const bf16x8*)(smem + base + 4096 + roff);
            #pragma unroll
            for (int i = 0; i < 3; ++i) {
                if (i < NT) {
                    acc[i][nt] = MFMA16(ah[i], bh, acc[i][nt]);
                    acc[i][nt] = MFMA16(al[i], bh, acc[i][nt]);
                    acc[i][nt] = MFMA16(ah[i], bl, acc[i][nt]);
                }
            }
        }

        // ---- convert + write kc+1 into buf[(kc+1)&1] ----
        if (kc < 7) {
            const int nb = ((kc + 1) & 1) * 8192;
            us8 h8, l8;
            #pragma unroll
            for (int j = 0; j < 8; ++j) {
                unsigned short hi = f2bf(vnext[j]);
                h8[j] = hi;
                l8[j] = f2bf(vnext[j] - bf2f(hi));
            }
            *(us8*)(smem + nb + woff) = h8;
            *(us8*)(smem + nb + 4096 + woff) = l8;
        }
        __syncthreads();
    }

    // ---- epilogue: bias add, split/pack into LDS, coalesced copy-out ----
    #pragma unroll
    for (int i = 0; i < 3; ++i) {
        if (i >= NT) continue;
        int tile = h ? (12 + w * 2 + i) : (w * 3 + i);
        if (tile < 4) {     // q/k (half 0 only)
            #pragma unroll
            for (int r = 0; r < 4; ++r) {
                int och = tile * 16 + quad * 4 + r;
                float bias = (och < 32) ? bq[och] : bk[och - 32];
                int arr = (och < 32) ? 0 : 2;
                int oq = och & 31;
                #pragma unroll
                for (int nt = 0; nt < 4; ++nt) {
                    float val = acc[i][nt][r] + bias;
                    if (och < 32) val *= LOG2E;
                    unsigned short hi = f2bf(val);
                    unsigned short lo = f2bf(val - bf2f(hi));
                    *(unsigned short*)(smem + arr * 4096 + (nt * 16 + l16) * 64 + oq * 2) = hi;
                    *(unsigned short*)(smem + (arr + 1) * 4096 + (nt * 16 + l16) * 64 + oq * 2) = lo;
                }
            }
        } else {            // v rows; local index 0..127 within this half
            #pragma unroll
            for (int r = 0; r < 4; ++r) {
                int vloc = tile * 16 + quad * 4 + r - (h ? 192 : 64);
                float bias = bv[vloc + (h ? 128 : 0)];
                int vb = h ? 0 : 16384;
                #pragma unroll
                for (int nt = 0; nt < 4; ++nt) {
                    *(unsigned short*)(smem + vb + vloc * 136 + (nt * 16 + l16) * 2)
                        = f2bf(acc[i][nt][r] + bias);
                }
            }
        }
    }
    __syncthreads();

    if (h == 0) {
        // copy-out q/k: 4 arrays x 64 rows x 64B
        unsigned short* dsts[4] = { qh, ql, kh, kl };
        int arr = t >> 6, nn2 = t & 63;
        unsigned short* dst = dsts[arr] + ((size_t)b * NN + n0 + nn2) * 32;
        #pragma unroll
        for (int i = 0; i < 4; ++i)
            *(us8*)(dst + i * 8) = *(const us8*)(smem + arr * 4096 + nn2 * 64 + i * 16);
        // copy-out v rows 0..127 (region at 16384)
        int voch = t >> 1, piece = t & 1;
        unsigned short* vd = vt + ((size_t)b * CH + voch) * NN + n0 + piece * 32;
        const unsigned char* src = smem + 16384 + voch * 136 + piece * 64;
        #pragma unroll
        for (int i = 0; i < 4; ++i)
            *(us8*)(vd + i * 8) = *(const us8*)(src + i * 16);
    } else {
        // copy-out v rows 128..255 (region at 0)
        int vloc = t >> 1, piece = t & 1;
        unsigned short* vd = vt + ((size_t)b * CH + vloc + 128) * NN + n0 + piece * 32;
        const unsigned char* src = smem + vloc * 136 + piece * 64;
        #pragma unroll
        for (int i = 0; i < 4; ++i)
            *(us8*)(vd + i * 8) = *(const us8*)(src + i * 16);
    }
}

// ---------------------------------------------------------------------------
// Kernel 3: MFMA flash attention -- ROUND-10/11/12 VERBATIM (proven
// 121-124us, FETCH 12.3MB): 512 blocks x 256 thr, b=blockIdx&7, 80KB LDS,
// V dbuf 2x32KB, P dbuf 2x8KB, ONE barrier/tile; E 12-MFMA setprio cluster
// then VALU cluster; PV 16 hoisted LDS reads then one 32-MFMA cluster.
// ---------------------------------------------------------------------------
#define A_P0 0          // P buffer 0: 64 rows x 128B
#define A_P1 8192       // P buffer 1
#define A_V0 16384      // V buffer 0: 256ch x 128B
#define A_V1 49152      // V buffer 1
#define A_SM 16384      // 256 floats, aliases V0 (post-loop only)

__global__ __launch_bounds__(256, 2) void attn_kernel(
    const unsigned short* __restrict__ qh, const unsigned short* __restrict__ ql,
    const unsigned short* __restrict__ kh, const unsigned short* __restrict__ kl,
    const unsigned short* __restrict__ vt, const float* __restrict__ gptr,
    float* __restrict__ out)
{
    __shared__ __align__(16) unsigned char smem[81920];
    const int t    = threadIdx.x;
    const int lane = t & 63;
    const int w    = t >> 6;
    const int l16  = lane & 15;
    const int quad = lane >> 4;
    const int b    = blockIdx.x & 7;
    const int n0   = (blockIdx.x >> 3) << 6;

    // Q B-frags (hi/lo); Q pre-scaled by log2e
    bf16x8 qhA[4], qlA[4];
    #pragma unroll
    for (int qt = 0; qt < 4; ++qt) {
        size_t row = (size_t)b * NN + n0 + qt * 16 + l16;
        qhA[qt] = *(const bf16x8*)(qh + row * 32 + quad * 8);
        qlA[qt] = *(const bf16x8*)(ql + row * 32 + quad * 8);
    }

    // K A-frag base: wave w owns keys w*16..+15 of each 64-key tile
    const unsigned short* khbase = kh + ((size_t)b * NN + w * 16 + l16) * 32 + quad * 8;
    const unsigned short* klbase = kl + ((size_t)b * NN + w * 16 + l16) * 32 + quad * 8;
    const unsigned char*  vtB    = (const unsigned char*)(vt + (size_t)b * CH * NN);

    // hoisted per-thread stage addresses
    const unsigned char* vsrc[8];
    int vlds[8];
    #pragma unroll
    for (int j = 0; j < 8; ++j) {
        int idx = j * 256 + t;
        int r = idx >> 3, cl = idx & 7;
        int cg = cl ^ (r & 7);
        vsrc[j] = vtB + (size_t)r * 8192 + cg * 16;   // tile-0 base
        vlds[j] = idx * 16;
    }
    // P-write offset (lane-constant): row = query l16, key chunk XOR row&7
    const int poff = l16 * 128 + ((((w << 1) | (quad >> 1)) ^ (l16 & 7)) << 4)
                   + ((quad & 1) << 3);

    f32x4 acc[4][4] = {};
    float S[4] = {};

    // prologue: K(0) regs first, then stage V(0) into V0
    bf16x8 kch = *(const bf16x8*)(khbase);
    bf16x8 kcl = *(const bf16x8*)(klbase);
    #pragma unroll
    for (int j = 0; j < 8; ++j)
        gload16(vsrc[j], smem + A_V0 + vlds[j]);

    #pragma unroll 1
    for (int tile = 0; tile < 64; ++tile) {
        unsigned char* P = smem + ((tile & 1) ? A_P1 : A_P0);

        // ---- E, MFMA cluster: all 12 MFMAs back-to-back ----
        f32x4 e4[4];
        __builtin_amdgcn_s_setprio(1);
        #pragma unroll
        for (int qt = 0; qt < 4; ++qt) {
            f32x4 e = { 0.f, 0.f, 0.f, 0.f };
            e = MFMA16(kch, qhA[qt], e);
            e = MFMA16(kch, qlA[qt], e);
            e = MFMA16(kcl, qhA[qt], e);
            e4[qt] = e;
        }
        __builtin_amdgcn_s_setprio(0);

        // ---- E, VALU cluster: exp2 / pack / S / P-write ----
        #pragma unroll
        for (int qt = 0; qt < 4; ++qt) {
            float p0 = exp2f(e4[qt][0]), p1 = exp2f(e4[qt][1]);
            float p2 = exp2f(e4[qt][2]), p3 = exp2f(e4[qt][3]);
            unsigned int u01, u23;
            asm("v_cvt_pk_bf16_f32 %0, %1, %2" : "=v"(u01) : "v"(p0), "v"(p1));
            asm("v_cvt_pk_bf16_f32 %0, %1, %2" : "=v"(u23) : "v"(p2), "v"(p3));
            // S sums the rounded values actually stored in P
            S[qt] += (__uint_as_float(u01 << 16) + __uint_as_float(u01 & 0xffff0000u))
                   + (__uint_as_float(u23 << 16) + __uint_as_float(u23 & 0xffff0000u));
            int2 pk2 = { (int)u01, (int)u23 };
            *(int2*)(P + qt * 2048 + poff) = pk2;
        }

        __syncthreads();   // P(tile) + V(tile) ready; prev PV reads drained

        // ---- post-barrier VMEM issue (consumed after NEXT barrier) ----
        const int m1 = ((tile + 1) & 63) * 64;
        bf16x8 knh = *(const bf16x8*)(khbase + (size_t)m1 * 32);
        bf16x8 knl = *(const bf16x8*)(klbase + (size_t)m1 * 32);
        if (tile < 63) {
            unsigned char* vdst = smem + ((tile & 1) ? A_V0 : A_V1);
            #pragma unroll
            for (int j = 0; j < 8; ++j) {
                vsrc[j] += 128;
                gload16(vsrc[j], vdst + vlds[j]);
            }
        }

        // ---- PV: hoist ALL 16 LDS reads, then one 32-MFMA cluster ----
        const unsigned char* VB = smem + ((tile & 1) ? A_V1 : A_V0);
        bf16x8 af0[4], af1[4], bf0[4], bf1[4];
        #pragma unroll
        for (int qt = 0; qt < 4; ++qt) {
            int row = qt * 16 + l16;
            af0[qt] = *(const bf16x8*)(P + row * 128
                                         + (((0 * 4 + quad) ^ (l16 & 7)) << 4));
            af1[qt] = *(const bf16x8*)(P + row * 128
                                         + (((1 * 4 + quad) ^ (l16 & 7)) << 4));
        }
        #pragma unroll
        for (int ct = 0; ct < 4; ++ct) {
            int vrow = w * 64 + ct * 16 + l16;
            bf0[ct] = *(const bf16x8*)(VB + vrow * 128
                                          + (((0 * 4 + quad) ^ (l16 & 7)) << 4));
            bf1[ct] = *(const bf16x8*)(VB + vrow * 128
                                          + (((1 * 4 + quad) ^ (l16 & 7)) << 4));
        }
        __builtin_amdgcn_s_setprio(1);
        #pragma unroll
        for (int qt = 0; qt < 4; ++qt)
            #pragma unroll
            for (int ct = 0; ct < 4; ++ct)
                acc[qt][ct] = MFMA16(af0[qt], bf0[ct], acc[qt][ct]);
        #pragma unroll
        for (int qt = 0; qt < 4; ++qt)
            #pragma unroll
            for (int ct = 0; ct < 4; ++ct)
                acc[qt][ct] = MFMA16(af1[qt], bf1[ct], acc[qt][ct]);
        __builtin_amdgcn_s_setprio(0);

        kch = knh;
        kcl = knl;
    }

    // S: reduce over quads (same query in lanes l16+16q), then across waves
    #pragma unroll
    for (int mask = 16; mask <= 32; mask <<= 1)
        #pragma unroll
        for (int qt = 0; qt < 4; ++qt)
            S[qt] += __shfl_xor(S[qt], mask);
    float* SM = (float*)(smem + A_SM);
    if (quad == 0) {
        #pragma unroll
        for (int qt = 0; qt < 4; ++qt)
            SM[w * 64 + qt * 16 + l16] = S[qt];
    }
    __syncthreads();

    const float g1 = 1.f + gptr[0];
    float* ob = out + (size_t)b * CH * NN;
    #pragma unroll
    for (int qt = 0; qt < 4; ++qt) {
        float is[4];
        #pragma unroll
        for (int r = 0; r < 4; ++r) {
            int qi = qt * 16 + quad * 4 + r;
            float Sf = SM[qi] + SM[64 + qi] + SM[128 + qi] + SM[192 + qi];
            is[r] = g1 / Sf;
        }
        #pragma unroll
        for (int ct = 0; ct < 4; ++ct) {
            float4 o4;
            o4.x = floorf(acc[qt][ct][0] * is[0] * 256.f) * 0.00390625f;
            o4.y = floorf(acc[qt][ct][1] * is[1] * 256.f) * 0.00390625f;
            o4.z = floorf(acc[qt][ct][2] * is[2] * 256.f) * 0.00390625f;
            o4.w = floorf(acc[qt][ct][3] * is[3] * 256.f) * 0.00390625f;
            *(float4*)(ob + (size_t)(w * 64 + ct * 16 + l16) * NN
                          + n0 + qt * 16 + quad * 4) = o4;
        }
    }
}

// ---------------------------------------------------------------------------
extern "C" void kernel_launch(void* const* d_in, const int* in_sizes, int n_in,
                              void* d_out, int out_size, void* d_ws, size_t ws_size,
                              hipStream_t stream) {
    const float* x  = (const float*)d_in[0];
    const float* wq = (const float*)d_in[1];
    const float* bq = (const float*)d_in[2];
    const float* wk = (const float*)d_in[3];
    const float* bk = (const float*)d_in[4];
    const float* wv = (const float*)d_in[5];
    const float* bv = (const float*)d_in[6];
    const float* gm = (const float*)d_in[7];
    float* out = (float*)d_out;

    unsigned short* ws = (unsigned short*)d_ws;
    const size_t WSZ = 320 * 256;               // 81,920
    const size_t QSZ = (size_t)BB * NN * 32;    // 1,048,576
    const size_t XSZ = (size_t)BB * NN * 256;   // 8,388,608
    unsigned short* wh = ws;
    unsigned short* wl = wh + WSZ;
    unsigned short* qh = wl + WSZ;
    unsigned short* ql = qh + QSZ;
    unsigned short* kh = ql + QSZ;
    unsigned short* kl = kh + QSZ;
    unsigned short* vt = kl + QSZ;              // vt size XSZ

    wsplit_kernel<<<320, 256, 0, stream>>>(wq, wk, wv, wh, wl);
    proj_kernel<<<1024, 256, 0, stream>>>(x, wh, wl, bq, bk, bv,
                                          qh, ql, kh, kl, vt);
    attn_kernel<<<512, 256, 0, stream>>>(qh, ql, kh, kl, vt, gm, out);
}